// Round 10
// baseline (670.662 us; speedup 1.0000x reference)
//
#include <hip/hip_runtime.h>
#include <hip/hip_cooperative_groups.h>
#include <stdint.h>

namespace cg = cooperative_groups;

#define NN 50000
#define NE 800000
#define NBG 391   // ceil(NN/128) GEMM tiles
#define NHB 3125  // hist blocks: 3125*256 == NE
#define NSB 98    // ceil(NN/512) scan chunks
#define NFB 782   // ceil(NN/64) final tiles

typedef __bf16 v8bf __attribute__((ext_vector_type(8)));
typedef float  v4f  __attribute__((ext_vector_type(4)));
typedef unsigned short v8us __attribute__((ext_vector_type(8)));

#define EXP2F(x) __builtin_amdgcn_exp2f(x)

__device__ __forceinline__ float bf2f(unsigned short u) {
    return __uint_as_float(((unsigned)u) << 16);
}
__device__ __forceinline__ unsigned short f2bf(float f) {
    unsigned u = __float_as_uint(f);
    u += 0x7FFFu + ((u >> 16) & 1u);   // round-to-nearest-even
    return (unsigned short)(u >> 16);
}
__device__ __forceinline__ float ldf(const void* p, size_t i, int isb) {
    return isb ? bf2f(((const unsigned short*)p)[i]) : ((const float*)p)[i];
}
__device__ __forceinline__ unsigned uminu(unsigned a, unsigned b) {
    return a < b ? a : b;
}
union bcast8 { v8us u; v8bf b; };

// ===========================================================================
// Phase bodies as __device__ functions — verbatim from the proven R4/R7
// kernels; called both by the cooperative pipes and the classic fallback.
// ===========================================================================

// ---- prep: b in [0,512) weights/BC/FLAG; b in [512,576) zero CNTP|DONE ----
__device__ __forceinline__ void dev_prep(
    int b, int j,
    const void* Wq, const void* bq, const void* Wk, const void* bk,
    const void* Wv, const void* bv, const void* Wa, const void* ba,
    const void* rel_att, const void* rel_msg, const void* rel_pri,
    unsigned* CNTP, int* FLAG, unsigned short* WTb, float* BC)
{
    if (b >= 512) {                       // zero CNTP(800000)+DONE(16)
        unsigned idx = (unsigned)(b - 512) * 128u + (unsigned)j;
        uint4 z = make_uint4(0, 0, 0, 0);
        #pragma unroll
        for (int t = 0; t < 25; ++t) {
            unsigned o = idx + (unsigned)t * 8192u;
            if (o < 200004u) ((uint4*)CNTP)[o] = z;
        }
        return;
    }
    const unsigned rp0 = ((const unsigned*)rel_pri)[0];
    const int isb = ((rp0 & 0xFFFFu) != 0u) ? 1 : 0;
    int m = b >> 7;
    int i = b & 127;          // k index
    if (b == 0 && j == 0) FLAG[0] = isb;
    if (m == 0) {
        WTb[((size_t)(0 * 128 + j)) * 128 + i] = f2bf(ldf(Wq, i * 128 + j, isb));
        if (i == 0) BC[j] = ldf(bq, j, isb);
    } else if (m == 3) {
        WTb[((size_t)(3 * 128 + j)) * 128 + i] = f2bf(ldf(Wa, i * 128 + j, isb));
        if (i == 0) BC[3 * 128 + j] = ldf(ba, j, isb);
    } else {
        const void* W    = (m == 1) ? Wk : Wv;
        const void* bias = (m == 1) ? bk : bv;
        const void* R    = (m == 1) ? rel_att : rel_msg;
        int hh = j >> 4, jj = j & 15;
        float scale = (m == 1) ? ldf(rel_pri, hh, isb) * 0.25f : 1.0f;
        float acc = 0.f, bacc = 0.f;
        #pragma unroll
        for (int l = 0; l < 16; ++l) {
            float r = ldf(R, hh * 256 + l * 16 + jj, isb);
            acc  += ldf(W, i * 128 + hh * 16 + l, isb) * r;
            bacc += ldf(bias, hh * 16 + l, isb) * r;
        }
        WTb[((size_t)(m * 128 + j)) * 128 + i] = f2bf(acc * scale);
        if (i == 0) BC[m * 128 + j] = bacc * scale;
    }
}

// ---- hist: one edge, return-atomic rank (R4-proven form) ----
__device__ __forceinline__ void dev_hist(
    int e, const int* dst, unsigned* CNTP, unsigned short* RANKS)
{
    unsigned r = atomicAdd(&CNTP[(unsigned)dst[e] << 4], 1u);
    RANKS[e] = (unsigned short)r;
}

// ---- QKV GEMM 128x128 two-LDS tile (R4-proven) ----
__device__ __forceinline__ void dev_gemm_qkv(
    int rowBase, int tid,
    unsigned short (*Ah)[136], unsigned short (*Bh)[136],
    const void* h, const unsigned short* WTb, const float* BC,
    const int* FLAG, unsigned short* Qb, unsigned short* KVb)
{
    const int isb = FLAG[0];
    if (isb) {
        #pragma unroll
        for (int i = 0; i < 8; ++i) {
            int lin = tid + i * 256;
            int row = lin >> 4, kc = (lin & 15) * 8;
            int gr = rowBase + row;
            uint4 u = make_uint4(0, 0, 0, 0);
            if (gr < NN) u = *(const uint4*)((const unsigned short*)h + (size_t)gr * 128 + kc);
            *(uint4*)&Ah[row][kc] = u;
        }
    } else {
        #pragma unroll
        for (int i = 0; i < 16; ++i) {
            int lin = tid + i * 256;
            int row = lin >> 5, c4 = (lin & 31) * 4;
            int gr = rowBase + row;
            ushort4 o = make_ushort4(0, 0, 0, 0);
            if (gr < NN) {
                float4 f = *(const float4*)((const float*)h + (size_t)gr * 128 + c4);
                o.x = f2bf(f.x); o.y = f2bf(f.y); o.z = f2bf(f.z); o.w = f2bf(f.w);
            }
            *(ushort4*)&Ah[row][c4] = o;
        }
    }

    const int w = tid >> 6, l = tid & 63;
    const int lr = l & 15, q = l >> 4;
    v4f accK[2][8];

    for (int m = 0; m < 3; ++m) {
        if (m) __syncthreads();
        #pragma unroll
        for (int i = 0; i < 8; ++i) {
            int lin = tid + i * 256;
            int col = lin >> 4, kc = (lin & 15) * 8;
            uint4 u = *(const uint4*)(WTb + ((size_t)(m * 128 + col)) * 128 + kc);
            *(uint4*)&Bh[col][kc] = u;
        }
        __syncthreads();

        v4f acc[2][8];
        #pragma unroll
        for (int rt = 0; rt < 2; ++rt)
            #pragma unroll
            for (int nt = 0; nt < 8; ++nt) {
                float bj = BC[m * 128 + nt * 16 + lr];
                acc[rt][nt] = (v4f){bj, bj, bj, bj};
            }
        #pragma unroll
        for (int kk = 0; kk < 4; ++kk) {
            v8bf a0 = *(const v8bf*)&Ah[w * 32 +  0 + lr][kk * 32 + q * 8];
            v8bf a1 = *(const v8bf*)&Ah[w * 32 + 16 + lr][kk * 32 + q * 8];
            #pragma unroll
            for (int nt = 0; nt < 8; ++nt) {
                v8bf b = *(const v8bf*)&Bh[nt * 16 + lr][kk * 32 + q * 8];
                acc[0][nt] = __builtin_amdgcn_mfma_f32_16x16x32_bf16(a0, b, acc[0][nt], 0, 0, 0);
                acc[1][nt] = __builtin_amdgcn_mfma_f32_16x16x32_bf16(a1, b, acc[1][nt], 0, 0, 0);
            }
        }
        if (m == 0) {
            #pragma unroll
            for (int rt = 0; rt < 2; ++rt)
                #pragma unroll
                for (int nt = 0; nt < 8; ++nt)
                    #pragma unroll
                    for (int r = 0; r < 4; ++r) {
                        int row = rowBase + w * 32 + rt * 16 + q * 4 + r;
                        if (row < NN)
                            Qb[(size_t)row * 128 + nt * 16 + lr] = f2bf(acc[rt][nt][r]);
                    }
        } else if (m == 1) {
            #pragma unroll
            for (int rt = 0; rt < 2; ++rt)
                #pragma unroll
                for (int nt = 0; nt < 8; ++nt) accK[rt][nt] = acc[rt][nt];
        } else {
            #pragma unroll
            for (int rt = 0; rt < 2; ++rt)
                #pragma unroll
                for (int nt = 0; nt < 8; ++nt)
                    #pragma unroll
                    for (int r = 0; r < 4; ++r) {
                        int row = rowBase + w * 32 + rt * 16 + q * 4 + r;
                        if (row < NN) {
                            ushort2 kv;
                            kv.x = f2bf(accK[rt][nt][r]);   // K channel
                            kv.y = f2bf(acc[rt][nt][r]);    // V channel
                            *(ushort2*)&KVb[(size_t)row * 256 + (nt * 16 + lr) * 2] = kv;
                        }
                    }
        }
    }
}

// ---- CSR scan chunk (512 nodes), last-chunk-block computes BOFF ----
__device__ __forceinline__ void dev_scan(
    int sb, int tid, unsigned* shs, int* lastFlagP,
    const unsigned* CNTP, unsigned* RPS, unsigned* BSUM,
    unsigned* BOFF, unsigned* DONE)
{
    int g0 = sb * 512 + tid * 2, g1 = g0 + 1;
    unsigned v0 = (g0 < NN) ? CNTP[(size_t)g0 << 4] : 0u;
    unsigned v1 = (g1 < NN) ? CNTP[(size_t)g1 << 4] : 0u;
    unsigned pv = v0 + v1;
    shs[tid] = pv;
    __syncthreads();
    #pragma unroll
    for (int off = 1; off < 256; off <<= 1) {
        unsigned t = 0;
        if (tid >= off) t = shs[tid - off];
        __syncthreads();
        if (tid >= off) shs[tid] += t;
        __syncthreads();
    }
    unsigned excl = shs[tid] - pv;
    if (g0 < NN) RPS[g0] = excl;
    if (g1 < NN) RPS[g1] = excl + v0;
    if (tid == 255) atomicExch(&BSUM[sb], shs[255]);
    __syncthreads();
    if (tid == 0) {
        __threadfence();
        *lastFlagP = (atomicAdd(DONE, 1u) == NSB - 1);
    }
    __syncthreads();
    if (*lastFlagP) {
        unsigned bv = (tid < NSB) ? atomicAdd(&BSUM[tid], 0u) : 0u;
        __syncthreads();
        shs[tid] = bv;
        __syncthreads();
        #pragma unroll
        for (int off = 1; off < 256; off <<= 1) {
            unsigned t = 0;
            if (tid >= off) t = shs[tid - off];
            __syncthreads();
            if (tid >= off) shs[tid] += t;
            __syncthreads();
        }
        if (tid < NSB) BOFF[tid] = shs[tid] - bv;
    }
    __syncthreads();
}

// ---- CSR fill (atomic-free) + ROW materialization ----
__device__ __forceinline__ void dev_fill(
    int t, const int* src, const int* dst, const unsigned short* RANKS,
    const unsigned* RPS, const unsigned* BOFF,
    unsigned short* ESRC, unsigned* ROW)
{
    if (t < NN) ROW[t] = RPS[t] + BOFF[t >> 9];
    if (t < NE / 2) {
        int e = t * 2;
        const int2 d2 = *(const int2*)(dst + e);
        const int2 s2 = *(const int2*)(src + e);
        const ushort2 r2 = *(const ushort2*)(RANKS + e);
        unsigned p0 = RPS[d2.x] + BOFF[d2.x >> 9] + r2.x;
        unsigned p1 = RPS[d2.y] + BOFF[d2.y >> 9] + r2.y;
        ESRC[p0] = (unsigned short)s2.x;
        ESRC[p1] = (unsigned short)s2.y;
    }
}

// ---- fused attention for one dst node (wave-wide), proven 55us structure --
__device__ __forceinline__ void dev_attn(
    int d, int lane,
    const unsigned* ROW, const unsigned short* ESRC,
    const unsigned short* Qb, const unsigned short* KVb,
    unsigned short* Tb)
{
    int hl = lane >> 5;        // which edge of the pair
    int sub = lane & 31;       // channel group
    const float LOG2E = 1.4426950408889634f;

    unsigned beg = ROW[d];
    unsigned end = (d == NN - 1) ? (unsigned)NE : ROW[d + 1];

    const ushort4 qu = *(const ushort4*)(Qb + (size_t)d * 128 + sub * 4);
    float q0 = bf2f(qu.x) * LOG2E, q1 = bf2f(qu.y) * LOG2E;
    float q2 = bf2f(qu.z) * LOG2E, q3 = bf2f(qu.w) * LOG2E;

    float s = 0.f, o0 = 0.f, o1 = 0.f, o2 = 0.f, o3 = 0.f;
    int n = (int)(end - beg);

#define ATT_F(kv) {                                                         \
        float p = q0 * bf2f(kv[0]) + q1 * bf2f(kv[2])                       \
                + q2 * bf2f(kv[4]) + q3 * bf2f(kv[6]);                      \
        p += __shfl_xor(p, 1);                                              \
        p += __shfl_xor(p, 2);                                              \
        float wgt = EXP2F(p);                                               \
        s  += wgt;                                                          \
        o0 += wgt * bf2f(kv[1]); o1 += wgt * bf2f(kv[3]);                   \
        o2 += wgt * bf2f(kv[5]); o3 += wgt * bf2f(kv[7]); }
#define ATT_T(kv, idx) {                                                    \
        float p = q0 * bf2f(kv[0]) + q1 * bf2f(kv[2])                       \
                + q2 * bf2f(kv[4]) + q3 * bf2f(kv[6]);                      \
        p += __shfl_xor(p, 1);                                              \
        p += __shfl_xor(p, 2);                                              \
        float wgt = ((idx) < end) ? EXP2F(p) : 0.f;                         \
        s  += wgt;                                                          \
        o0 += wgt * bf2f(kv[1]); o1 += wgt * bf2f(kv[3]);                   \
        o2 += wgt * bf2f(kv[5]); o3 += wgt * bf2f(kv[7]); }
#define GATH(sid) (*(const v8us*)(KVB + (((unsigned)(sid) << 9) + voff)))

    if (n > 0) {
        const unsigned char* KVB = (const unsigned char*)KVb;
        const unsigned voff = (unsigned)(sub * 16);
        const unsigned last = end - 1;
        const int RT = (n + 7) >> 3;
        const int tail = n & 7;
        const unsigned b0 = beg + (unsigned)hl;

        unsigned sA0 = ESRC[uminu(b0 + 0u, last)];
        unsigned sA1 = ESRC[uminu(b0 + 2u, last)];
        unsigned sA2 = ESRC[uminu(b0 + 4u, last)];
        unsigned sA3 = ESRC[uminu(b0 + 6u, last)];
        v8us kA0 = GATH(sA0), kA1 = GATH(sA1), kA2 = GATH(sA2), kA3 = GATH(sA3);
        unsigned sB0 = 0, sB1 = 0, sB2 = 0, sB3 = 0;
        if (RT > 1) {
            unsigned b1 = b0 + 8u;
            sB0 = ESRC[uminu(b1 + 0u, last)];
            sB1 = ESRC[uminu(b1 + 2u, last)];
            sB2 = ESRC[uminu(b1 + 4u, last)];
            sB3 = ESRC[uminu(b1 + 6u, last)];
        }

        for (int r = 0; r < RT; ++r) {
            v8us kB0 = kA0, kB1 = kA1, kB2 = kA2, kB3 = kA3;
            if (r + 1 < RT) {
                kB0 = GATH(sB0); kB1 = GATH(sB1);
                kB2 = GATH(sB2); kB3 = GATH(sB3);
            }
            unsigned sC0 = sB0, sC1 = sB1, sC2 = sB2, sC3 = sB3;
            if (r + 2 < RT) {
                unsigned b2 = b0 + (unsigned)(8 * (r + 2));
                sC0 = ESRC[uminu(b2 + 0u, last)];
                sC1 = ESRC[uminu(b2 + 2u, last)];
                sC2 = ESRC[uminu(b2 + 4u, last)];
                sC3 = ESRC[uminu(b2 + 6u, last)];
            }
            if (r == RT - 1 && tail) {
                unsigned base = beg + (unsigned)(8 * r) + (unsigned)hl;
                ATT_T(kA0, base + 0u);
                ATT_T(kA1, base + 2u);
                ATT_T(kA2, base + 4u);
                ATT_T(kA3, base + 6u);
            } else {
                ATT_F(kA0); ATT_F(kA1); ATT_F(kA2); ATT_F(kA3);
            }
            kA0 = kB0; kA1 = kB1; kA2 = kB2; kA3 = kB3;
            sB0 = sC0; sB1 = sC1; sB2 = sC2; sB3 = sC3;
        }
    }
#undef ATT_F
#undef ATT_T
#undef GATH

    s  += __shfl_xor(s, 32);
    o0 += __shfl_xor(o0, 32);
    o1 += __shfl_xor(o1, 32);
    o2 += __shfl_xor(o2, 32);
    o3 += __shfl_xor(o3, 32);
    float r = (s > 0.f) ? (1.0f / s) : 0.f;
    if (hl == 0) {
        ushort4 o;
        o.x = f2bf(o0 * r); o.y = f2bf(o1 * r);
        o.z = f2bf(o2 * r); o.w = f2bf(o3 * r);
        *(ushort4*)(Tb + (size_t)d * 128 + sub * 4) = o;
    }
}

// ---- final GEMM 64-row A-LDS / B-direct (R7-proven) + skip blend ----
__device__ __forceinline__ void dev_final(
    int rowBase, int tid, unsigned short (*Ah)[136],
    const unsigned short* Tb, const unsigned short* WTb, const float* BC,
    const void* h, const void* skip, const int* FLAG, void* out)
{
    const int isb = FLAG[0];
    #pragma unroll
    for (int i = 0; i < 4; ++i) {
        int lin = tid + i * 256;
        int row = lin >> 4, kc = (lin & 15) * 8;
        int gr = rowBase + row;
        uint4 u = make_uint4(0, 0, 0, 0);
        if (gr < NN) u = *(const uint4*)(Tb + (size_t)gr * 128 + kc);
        *(uint4*)&Ah[row][kc] = u;
    }
    __syncthreads();

    const int w = tid >> 6, l = tid & 63;
    const int lr = l & 15, q = l >> 4;

    v8bf a[4];
    #pragma unroll
    for (int kk = 0; kk < 4; ++kk)
        a[kk] = *(const v8bf*)&Ah[w * 16 + lr][kk * 32 + q * 8];

    v4f acc[8];
    #pragma unroll
    for (int nt = 0; nt < 8; ++nt) {
        float bj = BC[3 * 128 + nt * 16 + lr];
        acc[nt] = (v4f){bj, bj, bj, bj};
    }
    #pragma unroll
    for (int kk = 0; kk < 4; ++kk) {
        #pragma unroll
        for (int nt = 0; nt < 8; ++nt) {
            bcast8 bb;
            bb.u = *(const v8us*)(WTb + ((size_t)(3 * 128 + nt * 16 + lr)) * 128
                                  + kk * 32 + q * 8);
            acc[nt] = __builtin_amdgcn_mfma_f32_16x16x32_bf16(a[kk], bb.b, acc[nt], 0, 0, 0);
        }
    }
    float skipv = ldf(skip, 0, isb);
    float alpha = 1.0f / (1.0f + __expf(-skipv));
    float beta = 1.0f - alpha;
    #pragma unroll
    for (int nt = 0; nt < 8; ++nt) {
        #pragma unroll
        for (int r = 0; r < 4; ++r) {
            int row = rowBase + w * 16 + q * 4 + r;
            if (row < NN) {
                size_t off = (size_t)row * 128 + nt * 16 + lr;
                float hv = ldf(h, off, isb);
                float o = alpha * acc[nt][r] + beta * hv;
                if (isb) ((unsigned short*)out)[off] = f2bf(o);
                else     ((float*)out)[off] = o;
            }
        }
    }
}

// ===========================================================================
// Cooperative pipes: 6 dispatches -> 2. Phase bodies unchanged; grid.sync()
// replaces dispatch boundaries (each boundary measured ~10us+ of overhead).
// ===========================================================================
__global__ __launch_bounds__(256, 2) void k_pipe1(
    const void* Wq, const void* bq, const void* Wk, const void* bk,
    const void* Wv, const void* bv, const void* Wa, const void* ba,
    const void* rel_att, const void* rel_msg, const void* rel_pri,
    const void* h, const int* dst, int* FLAG, unsigned short* WTb, float* BC,
    unsigned* CNTP, unsigned short* RANKS, unsigned short* Qb, unsigned short* KVb,
    unsigned* RPS, unsigned* BSUM, unsigned* BOFF, unsigned* DONE)
{
    cg::grid_group grid = cg::this_grid();
    __shared__ __align__(16) unsigned short Ah[128][136];
    __shared__ __align__(16) unsigned short Bh[128][136];
    __shared__ int lastFlag;
    const int tid = threadIdx.x;
    const int nb = gridDim.x;

    // Phase A: weights/BC/FLAG + zero CNTP|DONE (576 work items of 128 thr)
    for (int wi = blockIdx.x; wi < 288; wi += nb) {
        int b = wi * 2 + (tid >> 7);
        dev_prep(b, tid & 127, Wq, bq, Wk, bk, Wv, bv, Wa, ba,
                 rel_att, rel_msg, rel_pri, CNTP, FLAG, WTb, BC);
    }
    grid.sync();

    // Phase B: GEMM tiles first (long blocks resident), hist backfills (R4)
    for (int wi = blockIdx.x; wi < NBG + NHB; wi += nb) {
        if (wi < NBG) {
            dev_gemm_qkv(wi * 128, tid, Ah, Bh, h, WTb, BC, FLAG, Qb, KVb);
            __syncthreads();
        } else {
            dev_hist((wi - NBG) * 256 + tid, dst, CNTP, RANKS);
        }
    }
    grid.sync();

    // Phase C: CSR scan
    unsigned* shs = (unsigned*)&Ah[0][0];
    for (int wi = blockIdx.x; wi < NSB; wi += nb)
        dev_scan(wi, tid, shs, &lastFlag, CNTP, RPS, BSUM, BOFF, DONE);
}

__global__ __launch_bounds__(256, 4) void k_pipe2(
    const int* src, const int* dst, const unsigned short* RANKS,
    const unsigned* RPS, const unsigned* BOFF,
    unsigned short* ESRC, unsigned* ROW,
    const unsigned short* Qb, const unsigned short* KVb, unsigned short* Tb,
    const unsigned short* WTb, const float* BC, const void* h,
    const void* skip, const int* FLAG, void* out)
{
    cg::grid_group grid = cg::this_grid();
    __shared__ __align__(16) unsigned short Ah[64][136];   // 17.4 KB
    const int tid = threadIdx.x;
    const int nb = gridDim.x;

    // Phase D: CSR fill + ROW (1563 work items)
    for (int wi = blockIdx.x; wi < 1563; wi += nb)
        dev_fill(wi * 256 + tid, src, dst, RANKS, RPS, BOFF, ESRC, ROW);
    grid.sync();

    // Phase E: fused attention (12500 work items, 4 nodes each)
    for (int wi = blockIdx.x; wi < 12500; wi += nb)
        dev_attn(wi * 4 + (tid >> 6), tid & 63, ROW, ESRC, Qb, KVb, Tb);
    grid.sync();

    // Phase F: final GEMM + skip blend (782 work items)
    for (int wi = blockIdx.x; wi < NFB; wi += nb) {
        dev_final(wi * 64, tid, Ah, Tb, WTb, BC, h, skip, FLAG, out);
        __syncthreads();
    }
}

// ===========================================================================
// Classic fallback kernels (thin wrappers) — used only if cooperative launch
// is rejected (e.g. capture incompatibility). Identical math.
// ===========================================================================
__global__ __launch_bounds__(128) void k_prep0c(
    const void* Wq, const void* bq, const void* Wk, const void* bk,
    const void* Wv, const void* bv, const void* Wa, const void* ba,
    const void* rel_att, const void* rel_msg, const void* rel_pri,
    unsigned* CNTP, int* FLAG, unsigned short* WTb, float* BC)
{
    dev_prep(blockIdx.x, threadIdx.x, Wq, bq, Wk, bk, Wv, bv, Wa, ba,
             rel_att, rel_msg, rel_pri, CNTP, FLAG, WTb, BC);
}

__global__ __launch_bounds__(256, 2) void k_qkvhc(
    const void* h, const unsigned short* WTb, const float* BC, const int* FLAG,
    unsigned short* Qb, unsigned short* KVb,
    const int* dst, unsigned* CNTP, unsigned short* RANKS)
{
    __shared__ __align__(16) unsigned short Ah[128][136];
    __shared__ __align__(16) unsigned short Bh[128][136];
    if (blockIdx.x < NBG)
        dev_gemm_qkv(blockIdx.x * 128, threadIdx.x, Ah, Bh, h, WTb, BC, FLAG, Qb, KVb);
    else
        dev_hist((blockIdx.x - NBG) * 256 + threadIdx.x, dst, CNTP, RANKS);
}

__global__ __launch_bounds__(256) void k_scanc(
    const unsigned* CNTP, unsigned* RPS, unsigned* BSUM,
    unsigned* BOFF, unsigned* DONE)
{
    __shared__ unsigned shs[256];
    __shared__ int lastFlag;
    dev_scan(blockIdx.x, threadIdx.x, shs, &lastFlag, CNTP, RPS, BSUM, BOFF, DONE);
}

__global__ __launch_bounds__(256) void k_fillc(
    const int* src, const int* dst, const unsigned short* RANKS,
    const unsigned* RPS, const unsigned* BOFF,
    unsigned short* ESRC, unsigned* ROW)
{
    dev_fill(blockIdx.x * 256 + threadIdx.x, src, dst, RANKS, RPS, BOFF, ESRC, ROW);
}

__global__ __launch_bounds__(256) void k_attnc(
    const unsigned* ROW, const unsigned short* ESRC,
    const unsigned short* Qb, const unsigned short* KVb, unsigned short* Tb)
{
    dev_attn((blockIdx.x * 256 + threadIdx.x) >> 6, threadIdx.x & 63,
             ROW, ESRC, Qb, KVb, Tb);
}

__global__ __launch_bounds__(256) void k_finalc(
    const unsigned short* Tb, const unsigned short* WTb, const float* BC,
    const void* h, const void* skip, const int* FLAG, void* out)
{
    __shared__ __align__(16) unsigned short Ah[64][136];
    dev_final(blockIdx.x * 64, threadIdx.x, Ah, Tb, WTb, BC, h, skip, FLAG, out);
}

// ---------------------------------------------------------------------------
// ws layout (u32 offsets): FLAG 16 | BC 512 | WTb 32768 | CNTP 800000 |
// DONE 16 | RANKS 400000 (800000 ushort) | RPS 50048 | BSUM 128 | BOFF 128 |
// ROW 50048 | Tb NN*128us | ESRC NE ushort | Qb NN*128us | KVb NN*256us
// ---------------------------------------------------------------------------
extern "C" void kernel_launch(void* const* d_in, const int* in_sizes, int n_in,
                              void* d_out, int out_size, void* d_ws, size_t ws_size,
                              hipStream_t stream)
{
    const void* h  = d_in[0];
    const int* src = (const int*)d_in[1];
    const int* dst = (const int*)d_in[2];
    const void* Wk = d_in[3];
    const void* bk = d_in[4];
    const void* Wq = d_in[5];
    const void* bq = d_in[6];
    const void* Wv = d_in[7];
    const void* bv = d_in[8];
    const void* Wa = d_in[9];
    const void* ba = d_in[10];
    const void* rel_att = d_in[11];
    const void* rel_msg = d_in[12];
    const void* rel_pri = d_in[13];
    const void* skip    = d_in[14];

    float* F = (float*)d_ws;
    int* FLAG      = (int*)F;
    float* BC      = F + 16;
    unsigned short* WTb = (unsigned short*)(BC + 512);
    unsigned* CNTP = (unsigned*)((float*)(BC + 512) + 32768);
    unsigned* DONE = CNTP + 800000;
    unsigned short* RANKS = (unsigned short*)(DONE + 16);
    unsigned* RPS  = (unsigned*)(RANKS + 800000);
    unsigned* BSUM = RPS + 50048;
    unsigned* BOFF = BSUM + 128;
    unsigned* ROW  = BOFF + 128;
    unsigned short* Tb = (unsigned short*)(ROW + 50048);
    unsigned short* ESRC = Tb + (size_t)NN * 128;
    unsigned short* Qb  = ESRC + NE;
    unsigned short* KVb = Qb + (size_t)NN * 128;

    void* p1[] = {
        (void*)&Wq, (void*)&bq, (void*)&Wk, (void*)&bk,
        (void*)&Wv, (void*)&bv, (void*)&Wa, (void*)&ba,
        (void*)&rel_att, (void*)&rel_msg, (void*)&rel_pri,
        (void*)&h, (void*)&dst, (void*)&FLAG, (void*)&WTb, (void*)&BC,
        (void*)&CNTP, (void*)&RANKS, (void*)&Qb, (void*)&KVb,
        (void*)&RPS, (void*)&BSUM, (void*)&BOFF, (void*)&DONE };
    hipError_t e1 = hipLaunchCooperativeKernel((void*)k_pipe1, dim3(512),
                                               dim3(256), p1, 0, stream);
    if (e1 != hipSuccess) {
        // classic fallback: prep -> qkvh -> scan
        k_prep0c<<<576, 128, 0, stream>>>(Wq, bq, Wk, bk, Wv, bv, Wa, ba,
                                          rel_att, rel_msg, rel_pri,
                                          CNTP, FLAG, WTb, BC);
        k_qkvhc<<<NBG + NHB, 256, 0, stream>>>(h, WTb, BC, FLAG, Qb, KVb,
                                               dst, CNTP, RANKS);
        k_scanc<<<NSB, 256, 0, stream>>>(CNTP, RPS, BSUM, BOFF, DONE);
    }

    void* p2[] = {
        (void*)&src, (void*)&dst, (void*)&RANKS, (void*)&RPS, (void*)&BOFF,
        (void*)&ESRC, (void*)&ROW, (void*)&Qb, (void*)&KVb, (void*)&Tb,
        (void*)&WTb, (void*)&BC, (void*)&h, (void*)&skip, (void*)&FLAG,
        (void*)&d_out };
    hipError_t e2 = hipLaunchCooperativeKernel((void*)k_pipe2, dim3(1024),
                                               dim3(256), p2, 0, stream);
    if (e2 != hipSuccess) {
        // classic fallback: fill -> attn -> final
        k_fillc<<<1563, 256, 0, stream>>>(src, dst, RANKS, RPS, BOFF, ESRC, ROW);
        k_attnc<<<12500, 256, 0, stream>>>(ROW, ESRC, Qb, KVb, Tb);
        k_finalc<<<NFB, 256, 0, stream>>>(Tb, WTb, BC, h, skip, FLAG, d_out);
    }
}

// Round 11
// 241.119 us; speedup vs baseline: 2.7815x; 2.7815x over previous
//
#include <hip/hip_runtime.h>
#include <stdint.h>

#define NN 50000
#define NE 800000
// DIM=128, HEADS=8, DK=16, rel_pri/sqrt(dk) folded into K-projection

typedef __bf16 v8bf __attribute__((ext_vector_type(8)));
typedef float  v4f  __attribute__((ext_vector_type(4)));
typedef unsigned short v8us __attribute__((ext_vector_type(8)));

#define EXP2F(x) __builtin_amdgcn_exp2f(x)   // v_exp_f32: 2^x

__device__ __forceinline__ float bf2f(unsigned short u) {
    return __uint_as_float(((unsigned)u) << 16);
}
__device__ __forceinline__ unsigned short f2bf(float f) {
    unsigned u = __float_as_uint(f);
    u += 0x7FFFu + ((u >> 16) & 1u);   // round-to-nearest-even
    return (unsigned short)(u >> 16);
}
__device__ __forceinline__ float ldf(const void* p, size_t i, int isb) {
    return isb ? bf2f(((const unsigned short*)p)[i]) : ((const float*)p)[i];
}
__device__ __forceinline__ unsigned uminu(unsigned a, unsigned b) {
    return a < b ? a : b;
}

// ---------------------------------------------------------------------------
// Prep: blocks 0..511 build combined bf16 weights (transposed [m][col][k]) +
// BC + FLAG. Blocks 512..575 zero CNTP|DONE (replaces the hipMemsetAsync
// dispatch: 800016 u32 = 200004 uint4 over 8192 threads).
// ---------------------------------------------------------------------------
__global__ __launch_bounds__(128) void k_prep0(
    const void* __restrict__ Wq, const void* __restrict__ bq,
    const void* __restrict__ Wk, const void* __restrict__ bk,
    const void* __restrict__ Wv, const void* __restrict__ bv,
    const void* __restrict__ Wa, const void* __restrict__ ba,
    const void* __restrict__ rel_att, const void* __restrict__ rel_msg,
    const void* __restrict__ rel_pri,
    unsigned* __restrict__ CNTP,
    int* __restrict__ FLAG, unsigned short* __restrict__ WTb,
    float* __restrict__ BC)
{
    int b = blockIdx.x;
    int j = threadIdx.x;
    if (b >= 512) {                       // zeroing part: CNTP(800000)+DONE(16)
        unsigned idx = (unsigned)(b - 512) * 128u + (unsigned)j;
        uint4 z = make_uint4(0, 0, 0, 0);
        #pragma unroll
        for (int t = 0; t < 25; ++t) {
            unsigned o = idx + (unsigned)t * 8192u;
            if (o < 200004u) ((uint4*)CNTP)[o] = z;
        }
        return;
    }
    const unsigned rp0 = ((const unsigned*)rel_pri)[0];
    const int isb = ((rp0 & 0xFFFFu) != 0u) ? 1 : 0;
    int m = b >> 7;
    int i = b & 127;          // k index
    if (b == 0 && j == 0) FLAG[0] = isb;
    if (m == 0) {
        WTb[((size_t)(0 * 128 + j)) * 128 + i] = f2bf(ldf(Wq, i * 128 + j, isb));
        if (i == 0) BC[j] = ldf(bq, j, isb);
    } else if (m == 3) {
        WTb[((size_t)(3 * 128 + j)) * 128 + i] = f2bf(ldf(Wa, i * 128 + j, isb));
        if (i == 0) BC[3 * 128 + j] = ldf(ba, j, isb);
    } else {
        const void* W    = (m == 1) ? Wk : Wv;
        const void* bias = (m == 1) ? bk : bv;
        const void* R    = (m == 1) ? rel_att : rel_msg;
        int hh = j >> 4, jj = j & 15;
        float scale = (m == 1) ? ldf(rel_pri, hh, isb) * 0.25f : 1.0f;
        float acc = 0.f, bacc = 0.f;
        #pragma unroll
        for (int l = 0; l < 16; ++l) {
            float r = ldf(R, hh * 256 + l * 16 + jj, isb);
            acc  += ldf(W, i * 128 + hh * 16 + l, isb) * r;
            bacc += ldf(bias, hh * 16 + l, isb) * r;
        }
        WTb[((size_t)(m * 128 + j)) * 128 + i] = f2bf(acc * scale);
        if (i == 0) BC[m * 128 + j] = bacc * scale;
    }
}

// ---------------------------------------------------------------------------
// Fused MFMA QKV GEMM + dst HISTOGRAM (independent work co-scheduled in one
// dispatch so they overlap on the single stream). R4-proven best (240.8us
// total): GEMM blocks FIRST (long blocks resident, hist backfills); R9's
// hist-first ordering regressed (62us vs 53-57us) and R10's persistent-wave
// version collapsed gather MLP (0.8 TB/s vs 3.5).
// Blocks 0..390: 128x128 GEMM tile, loop m=0..2 (A staged once); K
//   accumulators held through the V pass, KV stored interleaved ushort2.
// Blocks 391..3515: histogram into line-padded CNTP[d*16]; atomic return
//   value IS the edge's rank within its dst bucket -> RANKS (ushort).
// ---------------------------------------------------------------------------
#define NBG 391   // ceil(NN/128)
#define NHB 3125  // 3125*256 == NE exactly
#define NSB 98    // ceil(NN/512)
__global__ __launch_bounds__(256, 2) void k_qkvh(
    const void* __restrict__ h, const unsigned short* __restrict__ WTb,
    const float* __restrict__ BC, const int* __restrict__ FLAG,
    unsigned short* __restrict__ Qb, unsigned short* __restrict__ KVb,
    const int* __restrict__ dst,
    unsigned* __restrict__ CNTP, unsigned short* __restrict__ RANKS)
{
    __shared__ __align__(16) unsigned short Ah[128][136];   // +8 pad
    __shared__ __align__(16) unsigned short Bh[128][136];
    const int tid = threadIdx.x;

    if (blockIdx.x >= NBG) {
        // ---------------- histogram part ----------------
        int e = (blockIdx.x - NBG) * 256 + tid;
        unsigned r = atomicAdd(&CNTP[(unsigned)dst[e] << 4], 1u);
        RANKS[e] = (unsigned short)r;
        return;
    }

    // ---------------- QKV GEMM part ----------------
    const int isb = FLAG[0];
    const int rowBase = blockIdx.x * 128;

    if (isb) {
        #pragma unroll
        for (int i = 0; i < 8; ++i) {
            int lin = tid + i * 256;
            int row = lin >> 4, kc = (lin & 15) * 8;
            int gr = rowBase + row;
            uint4 u = make_uint4(0, 0, 0, 0);
            if (gr < NN) u = *(const uint4*)((const unsigned short*)h + (size_t)gr * 128 + kc);
            *(uint4*)&Ah[row][kc] = u;
        }
    } else {
        #pragma unroll
        for (int i = 0; i < 16; ++i) {
            int lin = tid + i * 256;
            int row = lin >> 5, c4 = (lin & 31) * 4;
            int gr = rowBase + row;
            ushort4 o = make_ushort4(0, 0, 0, 0);
            if (gr < NN) {
                float4 f = *(const float4*)((const float*)h + (size_t)gr * 128 + c4);
                o.x = f2bf(f.x); o.y = f2bf(f.y); o.z = f2bf(f.z); o.w = f2bf(f.w);
            }
            *(ushort4*)&Ah[row][c4] = o;
        }
    }

    const int w = tid >> 6, l = tid & 63;
    const int lr = l & 15, q = l >> 4;
    v4f accK[2][8];

    for (int m = 0; m < 3; ++m) {
        if (m) __syncthreads();
        #pragma unroll
        for (int i = 0; i < 8; ++i) {
            int lin = tid + i * 256;
            int col = lin >> 4, kc = (lin & 15) * 8;
            uint4 u = *(const uint4*)(WTb + ((size_t)(m * 128 + col)) * 128 + kc);
            *(uint4*)&Bh[col][kc] = u;
        }
        __syncthreads();

        v4f acc[2][8];
        #pragma unroll
        for (int rt = 0; rt < 2; ++rt)
            #pragma unroll
            for (int nt = 0; nt < 8; ++nt) {
                float bj = BC[m * 128 + nt * 16 + lr];
                acc[rt][nt] = (v4f){bj, bj, bj, bj};
            }
        #pragma unroll
        for (int kk = 0; kk < 4; ++kk) {
            v8bf a0 = *(const v8bf*)&Ah[w * 32 +  0 + lr][kk * 32 + q * 8];
            v8bf a1 = *(const v8bf*)&Ah[w * 32 + 16 + lr][kk * 32 + q * 8];
            #pragma unroll
            for (int nt = 0; nt < 8; ++nt) {
                v8bf b = *(const v8bf*)&Bh[nt * 16 + lr][kk * 32 + q * 8];
                acc[0][nt] = __builtin_amdgcn_mfma_f32_16x16x32_bf16(a0, b, acc[0][nt], 0, 0, 0);
                acc[1][nt] = __builtin_amdgcn_mfma_f32_16x16x32_bf16(a1, b, acc[1][nt], 0, 0, 0);
            }
        }
        if (m == 0) {
            #pragma unroll
            for (int rt = 0; rt < 2; ++rt)
                #pragma unroll
                for (int nt = 0; nt < 8; ++nt)
                    #pragma unroll
                    for (int r = 0; r < 4; ++r) {
                        int row = rowBase + w * 32 + rt * 16 + q * 4 + r;
                        if (row < NN)
                            Qb[(size_t)row * 128 + nt * 16 + lr] = f2bf(acc[rt][nt][r]);
                    }
        } else if (m == 1) {
            #pragma unroll
            for (int rt = 0; rt < 2; ++rt)
                #pragma unroll
                for (int nt = 0; nt < 8; ++nt) accK[rt][nt] = acc[rt][nt];
        } else {
            #pragma unroll
            for (int rt = 0; rt < 2; ++rt)
                #pragma unroll
                for (int nt = 0; nt < 8; ++nt)
                    #pragma unroll
                    for (int r = 0; r < 4; ++r) {
                        int row = rowBase + w * 32 + rt * 16 + q * 4 + r;
                        if (row < NN) {
                            ushort2 kv;
                            kv.x = f2bf(accK[rt][nt][r]);   // K channel
                            kv.y = f2bf(acc[rt][nt][r]);    // V channel
                            *(ushort2*)&KVb[(size_t)row * 256 + (nt * 16 + lr) * 2] = kv;
                        }
                    }
        }
    }
}

// ---------------------------------------------------------------------------
// CSR scan (512 nodes/block), last-block pattern -> BOFF.
// ---------------------------------------------------------------------------
__global__ __launch_bounds__(256) void k_scan(
    const unsigned* __restrict__ CNTP,
    unsigned* __restrict__ RPS, unsigned* __restrict__ BSUM,
    unsigned* __restrict__ BOFF, unsigned* __restrict__ DONE)
{
    __shared__ unsigned shs[256];
    __shared__ int lastFlag;
    const int tid = threadIdx.x;
    int sb = blockIdx.x;
    int g0 = sb * 512 + tid * 2, g1 = g0 + 1;
    unsigned v0 = (g0 < NN) ? CNTP[(size_t)g0 << 4] : 0u;
    unsigned v1 = (g1 < NN) ? CNTP[(size_t)g1 << 4] : 0u;
    unsigned pv = v0 + v1;
    shs[tid] = pv;
    __syncthreads();
    #pragma unroll
    for (int off = 1; off < 256; off <<= 1) {
        unsigned t = 0;
        if (tid >= off) t = shs[tid - off];
        __syncthreads();
        if (tid >= off) shs[tid] += t;
        __syncthreads();
    }
    unsigned excl = shs[tid] - pv;
    if (g0 < NN) RPS[g0] = excl;
    if (g1 < NN) RPS[g1] = excl + v0;
    if (tid == 255) atomicExch(&BSUM[sb], shs[255]);
    __syncthreads();
    if (tid == 0) {
        __threadfence();
        lastFlag = (atomicAdd(DONE, 1u) == NSB - 1);
    }
    __syncthreads();
    if (!lastFlag) return;
    unsigned bv = (tid < NSB) ? atomicAdd(&BSUM[tid], 0u) : 0u;
    __syncthreads();
    shs[tid] = bv;
    __syncthreads();
    #pragma unroll
    for (int off = 1; off < 256; off <<= 1) {
        unsigned t = 0;
        if (tid >= off) t = shs[tid - off];
        __syncthreads();
        if (tid >= off) shs[tid] += t;
        __syncthreads();
    }
    if (tid < NSB) BOFF[tid] = shs[tid] - bv;
}

// ---------------------------------------------------------------------------
// CSR fill, ATOMIC-FREE: pos = RPS[d] + BOFF + RANKS[e]. ESRC is ushort.
// Also materializes ROW[d] = RPS[d] + BOFF[d>>9] for k_attn's startup.
// ---------------------------------------------------------------------------
__global__ __launch_bounds__(256) void k_fill(
    const int* __restrict__ src, const int* __restrict__ dst,
    const unsigned short* __restrict__ RANKS,
    const unsigned* __restrict__ RPS, const unsigned* __restrict__ BOFF,
    unsigned short* __restrict__ ESRC, unsigned* __restrict__ ROW)
{
    int t = blockIdx.x * 256 + threadIdx.x;
    if (t < NN) ROW[t] = RPS[t] + BOFF[t >> 9];
    if (t >= NE / 2) return;
    int e = t * 2;
    const int2 d2 = *(const int2*)(dst + e);
    const int2 s2 = *(const int2*)(src + e);
    const ushort2 r2 = *(const ushort2*)(RANKS + e);
    unsigned p0 = RPS[d2.x] + BOFF[d2.x >> 9] + r2.x;
    unsigned p1 = RPS[d2.y] + BOFF[d2.y >> 9] + r2.y;
    ESRC[p0] = (unsigned short)s2.x;
    ESRC[p1] = (unsigned short)s2.y;
}

// ---------------------------------------------------------------------------
// Fused attention: one wave per dst node, 32 lanes per edge (2 edges/round),
// 8-edge rounds. Depth-2 software pipeline. Full rounds unmasked; only the
// tail round predicates. 32-bit gather offsets. No-max softmax.
// At a pattern-specific memory-system ceiling: L2-miss traffic 179.6 MB
// equals the structural minimum (8 XCDs x 50K*(1-e^-2) rows x 512B) and
// delivery saturates ~3.5 TB/s. Short-lived waves (one node each) are
// ESSENTIAL: R10's persistent-wave version collapsed to 0.8 TB/s.
// ---------------------------------------------------------------------------
__global__ __launch_bounds__(256) void k_attn(
    const unsigned* __restrict__ ROW,
    const unsigned short* __restrict__ ESRC,
    const unsigned short* __restrict__ Qb, const unsigned short* __restrict__ KVb,
    unsigned short* __restrict__ Tb)
{
    int d = (blockIdx.x * 256 + threadIdx.x) >> 6;
    int lane = threadIdx.x & 63;
    int hl = lane >> 5;        // which edge of the pair
    int sub = lane & 31;       // channel group: channels sub*4 .. sub*4+3
    const float LOG2E = 1.4426950408889634f;

    unsigned beg = ROW[d];
    unsigned end = (d == NN - 1) ? (unsigned)NE : ROW[d + 1];

    const ushort4 qu = *(const ushort4*)(Qb + (size_t)d * 128 + sub * 4);
    float q0 = bf2f(qu.x) * LOG2E, q1 = bf2f(qu.y) * LOG2E;
    float q2 = bf2f(qu.z) * LOG2E, q3 = bf2f(qu.w) * LOG2E;

    float s = 0.f, o0 = 0.f, o1 = 0.f, o2 = 0.f, o3 = 0.f;
    int n = (int)(end - beg);

    // kv layout per lane: [K0,V0,K1,V1,K2,V2,K3,V3] for channels sub*4..+3
#define ATT_F(kv) {                                                         \
        float p = q0 * bf2f(kv[0]) + q1 * bf2f(kv[2])                       \
                + q2 * bf2f(kv[4]) + q3 * bf2f(kv[6]);                      \
        p += __shfl_xor(p, 1);                                              \
        p += __shfl_xor(p, 2);                                              \
        float wgt = EXP2F(p);                                               \
        s  += wgt;                                                          \
        o0 += wgt * bf2f(kv[1]); o1 += wgt * bf2f(kv[3]);                   \
        o2 += wgt * bf2f(kv[5]); o3 += wgt * bf2f(kv[7]); }
#define ATT_T(kv, idx) {                                                    \
        float p = q0 * bf2f(kv[0]) + q1 * bf2f(kv[2])                       \
                + q2 * bf2f(kv[4]) + q3 * bf2f(kv[6]);                      \
        p += __shfl_xor(p, 1);                                              \
        p += __shfl_xor(p, 2);                                              \
        float wgt = ((idx) < end) ? EXP2F(p) : 0.f;                         \
        s  += wgt;                                                          \
        o0 += wgt * bf2f(kv[1]); o1 += wgt * bf2f(kv[3]);                   \
        o2 += wgt * bf2f(kv[5]); o3 += wgt * bf2f(kv[7]); }
#define GATH(sid) (*(const v8us*)(KVB + (((unsigned)(sid) << 9) + voff)))

    if (n > 0) {
        const unsigned char* KVB = (const unsigned char*)KVb;
        const unsigned voff = (unsigned)(sub * 16);   // byte offset in KV row
        const unsigned last = end - 1;
        const int RT = (n + 7) >> 3;                  // 8-edge rounds
        const int tail = n & 7;                       // 0 => last round full
        const unsigned b0 = beg + (unsigned)hl;

        // round 0 sids + gathers
        unsigned sA0 = ESRC[uminu(b0 + 0u, last)];
        unsigned sA1 = ESRC[uminu(b0 + 2u, last)];
        unsigned sA2 = ESRC[uminu(b0 + 4u, last)];
        unsigned sA3 = ESRC[uminu(b0 + 6u, last)];
        v8us kA0 = GATH(sA0), kA1 = GATH(sA1), kA2 = GATH(sA2), kA3 = GATH(sA3);
        // round 1 sids
        unsigned sB0 = 0, sB1 = 0, sB2 = 0, sB3 = 0;
        if (RT > 1) {
            unsigned b1 = b0 + 8u;
            sB0 = ESRC[uminu(b1 + 0u, last)];
            sB1 = ESRC[uminu(b1 + 2u, last)];
            sB2 = ESRC[uminu(b1 + 4u, last)];
            sB3 = ESRC[uminu(b1 + 6u, last)];
        }

        for (int r = 0; r < RT; ++r) {
            v8us kB0 = kA0, kB1 = kA1, kB2 = kA2, kB3 = kA3;
            if (r + 1 < RT) {            // KV gathers for round r+1
                kB0 = GATH(sB0); kB1 = GATH(sB1);
                kB2 = GATH(sB2); kB3 = GATH(sB3);
            }
            unsigned sC0 = sB0, sC1 = sB1, sC2 = sB2, sC3 = sB3;
            if (r + 2 < RT) {            // sids for round r+2
                unsigned b2 = b0 + (unsigned)(8 * (r + 2));
                sC0 = ESRC[uminu(b2 + 0u, last)];
                sC1 = ESRC[uminu(b2 + 2u, last)];
                sC2 = ESRC[uminu(b2 + 4u, last)];
                sC3 = ESRC[uminu(b2 + 6u, last)];
            }
            if (r == RT - 1 && tail) {   // masked tail round
                unsigned base = beg + (unsigned)(8 * r) + (unsigned)hl;
                ATT_T(kA0, base + 0u);
                ATT_T(kA1, base + 2u);
                ATT_T(kA2, base + 4u);
                ATT_T(kA3, base + 6u);
            } else {                     // full round: no predication
                ATT_F(kA0); ATT_F(kA1); ATT_F(kA2); ATT_F(kA3);
            }
            kA0 = kB0; kA1 = kB1; kA2 = kB2; kA3 = kB3;
            sB0 = sC0; sB1 = sC1; sB2 = sC2; sB3 = sC3;
        }
    }
#undef ATT_F
#undef ATT_T
#undef GATH

    // combine the two 32-lane halves
    s  += __shfl_xor(s, 32);
    o0 += __shfl_xor(o0, 32);
    o1 += __shfl_xor(o1, 32);
    o2 += __shfl_xor(o2, 32);
    o3 += __shfl_xor(o3, 32);
    float r = (s > 0.f) ? (1.0f / s) : 0.f;
    if (hl == 0) {
        ushort4 o;
        o.x = f2bf(o0 * r); o.y = f2bf(o1 * r);
        o.z = f2bf(o2 * r); o.w = f2bf(o3 * r);
        *(ushort4*)(Tb + (size_t)d * 128 + sub * 4) = o;
    }
}

// ---------------------------------------------------------------------------
// MFMA final GEMM + sigmoid-skip blend. T is bf16 (A-tile copied raw).
// 128-row tile, 391 blocks, two-LDS structure (R4-proven).
// ---------------------------------------------------------------------------
__global__ __launch_bounds__(256, 2) void k_final_m(
    const unsigned short* __restrict__ Tb, const unsigned short* __restrict__ WTb,
    const float* __restrict__ BC, const void* __restrict__ h,
    const void* __restrict__ skip, const int* __restrict__ FLAG,
    void* __restrict__ out)
{
    __shared__ __align__(16) unsigned short Ah[128][136];
    __shared__ __align__(16) unsigned short Bh[128][136];
    const int isb = FLAG[0];
    const int tid = threadIdx.x;
    const int rowBase = blockIdx.x * 128;

    #pragma unroll
    for (int i = 0; i < 8; ++i) {
        int lin = tid + i * 256;
        int row = lin >> 4, kc = (lin & 15) * 8;
        int gr = rowBase + row;
        uint4 u = make_uint4(0, 0, 0, 0);
        if (gr < NN) u = *(const uint4*)(Tb + (size_t)gr * 128 + kc);
        *(uint4*)&Ah[row][kc] = u;
    }
    #pragma unroll
    for (int i = 0; i < 8; ++i) {
        int lin = tid + i * 256;
        int col = lin >> 4, kc = (lin & 15) * 8;
        uint4 u = *(const uint4*)(WTb + ((size_t)(3 * 128 + col)) * 128 + kc);
        *(uint4*)&Bh[col][kc] = u;
    }
    __syncthreads();

    const int w = tid >> 6, l = tid & 63;
    const int lr = l & 15, q = l >> 4;
    v4f acc[2][8];
    #pragma unroll
    for (int rt = 0; rt < 2; ++rt)
        #pragma unroll
        for (int nt = 0; nt < 8; ++nt) {
            float bj = BC[3 * 128 + nt * 16 + lr];
            acc[rt][nt] = (v4f){bj, bj, bj, bj};
        }
    #pragma unroll
    for (int kk = 0; kk < 4; ++kk) {
        v8bf a0 = *(const v8bf*)&Ah[w * 32 +  0 + lr][kk * 32 + q * 8];
        v8bf a1 = *(const v8bf*)&Ah[w * 32 + 16 + lr][kk * 32 + q * 8];
        #pragma unroll
        for (int nt = 0; nt < 8; ++nt) {
            v8bf b = *(const v8bf*)&Bh[nt * 16 + lr][kk * 32 + q * 8];
            acc[0][nt] = __builtin_amdgcn_mfma_f32_16x16x32_bf16(a0, b, acc[0][nt], 0, 0, 0);
            acc[1][nt] = __builtin_amdgcn_mfma_f32_16x16x32_bf16(a1, b, acc[1][nt], 0, 0, 0);
        }
    }
    float skipv = ldf(skip, 0, isb);
    float alpha = 1.0f / (1.0f + __expf(-skipv));
    float beta = 1.0f - alpha;
    #pragma unroll
    for (int rt = 0; rt < 2; ++rt)
        #pragma unroll
        for (int nt = 0; nt < 8; ++nt) {
            #pragma unroll
            for (int r = 0; r < 4; ++r) {
                int row = rowBase + w * 32 + rt * 16 + q * 4 + r;
                if (row < NN) {
                    size_t off = (size_t)row * 128 + nt * 16 + lr;
                    float hv = ldf(h, off, isb);
                    float o = alpha * acc[rt][nt][r] + beta * hv;
                    if (isb) ((unsigned short*)out)[off] = f2bf(o);
                    else     ((float*)out)[off] = o;
                }
            }
        }
}

// ---------------------------------------------------------------------------
// ws layout (u32 offsets): FLAG 16 | BC 512 | WTb 32768 | CNTP 800000 |
// DONE 16 | RANKS 400000 (800000 ushort) | RPS 50048 | BSUM 128 | BOFF 128 |
// ROW 50048 | Tb NN*128us | ESRC NE ushort | Qb NN*128us | KVb NN*256us
// total ~58 MB
// ---------------------------------------------------------------------------
extern "C" void kernel_launch(void* const* d_in, const int* in_sizes, int n_in,
                              void* d_out, int out_size, void* d_ws, size_t ws_size,
                              hipStream_t stream)
{
    const void* h  = d_in[0];
    const int* src = (const int*)d_in[1];
    const int* dst = (const int*)d_in[2];
    const void* Wk = d_in[3];
    const void* bk = d_in[4];
    const void* Wq = d_in[5];
    const void* bq = d_in[6];
    const void* Wv = d_in[7];
    const void* bv = d_in[8];
    const void* Wa = d_in[9];
    const void* ba = d_in[10];
    const void* rel_att = d_in[11];
    const void* rel_msg = d_in[12];
    const void* rel_pri = d_in[13];
    const void* skip    = d_in[14];

    float* F = (float*)d_ws;
    int* FLAG      = (int*)F;
    float* BC      = F + 16;
    unsigned short* WTb = (unsigned short*)(BC + 512);
    unsigned* CNTP = (unsigned*)((float*)(BC + 512) + 32768);
    unsigned* DONE = CNTP + 800000;
    unsigned short* RANKS = (unsigned short*)(DONE + 16);
    unsigned* RPS  = (unsigned*)(RANKS + 800000);
    unsigned* BSUM = RPS + 50048;
    unsigned* BOFF = BSUM + 128;
    unsigned* ROW  = BOFF + 128;
    unsigned short* Tb = (unsigned short*)(ROW + 50048);
    unsigned short* ESRC = Tb + (size_t)NN * 128;
    unsigned short* Qb  = ESRC + NE;
    unsigned short* KVb = Qb + (size_t)NN * 128;

    // 1. weights/BC/FLAG + zero CNTP|DONE (memset folded in)
    k_prep0<<<512 + 64, 128, 0, stream>>>(Wq, bq, Wk, bk, Wv, bv, Wa, ba,
                                          rel_att, rel_msg, rel_pri,
                                          CNTP, FLAG, WTb, BC);
    // 2. QKV GEMM (first in grid) overlapped with dst histogram
    k_qkvh<<<NBG + NHB, 256, 0, stream>>>(h, WTb, BC, FLAG, Qb, KVb,
                                          dst, CNTP, RANKS);
    // 3. CSR scan
    k_scan<<<NSB, 256, 0, stream>>>(CNTP, RPS, BSUM, BOFF, DONE);
    // 4. CSR fill + ROW
    k_fill<<<(NE / 2 + 255) / 256, 256, 0, stream>>>(src, dst, RANKS, RPS, BOFF, ESRC, ROW);
    // 5. fused attention
    k_attn<<<(NN * 64) / 256, 256, 0, stream>>>(ROW, ESRC, Qb, KVb, Tb);
    // 6. final GEMM + skip blend
    k_final_m<<<NBG, 256, 0, stream>>>(Tb, WTb, BC, h, skip, FLAG, d_out);
}

// Round 12
// 240.547 us; speedup vs baseline: 2.7881x; 1.0024x over previous
//
#include <hip/hip_runtime.h>
#include <stdint.h>

#define NN 50000
#define NE 800000
// DIM=128, HEADS=8, DK=16, rel_pri/sqrt(dk) folded into K-projection

typedef __bf16 v8bf __attribute__((ext_vector_type(8)));
typedef float  v4f  __attribute__((ext_vector_type(4)));
typedef unsigned short v8us __attribute__((ext_vector_type(8)));

#define EXP2F(x) __builtin_amdgcn_exp2f(x)   // v_exp_f32: 2^x

__device__ __forceinline__ float bf2f(unsigned short u) {
    return __uint_as_float(((unsigned)u) << 16);
}
__device__ __forceinline__ unsigned short f2bf(float f) {
    unsigned u = __float_as_uint(f);
    u += 0x7FFFu + ((u >> 16) & 1u);   // round-to-nearest-even
    return (unsigned short)(u >> 16);
}
__device__ __forceinline__ float ldf(const void* p, size_t i, int isb) {
    return isb ? bf2f(((const unsigned short*)p)[i]) : ((const float*)p)[i];
}
__device__ __forceinline__ unsigned uminu(unsigned a, unsigned b) {
    return a < b ? a : b;
}

// ---------------------------------------------------------------------------
// Prep: blocks 0..511 build combined bf16 weights (transposed [m][col][k]) +
// BC + FLAG. Blocks 512..575 zero CNTP|DONE (replaces the hipMemsetAsync
// dispatch: 800016 u32 = 200004 uint4 over 8192 threads).
// ---------------------------------------------------------------------------
__global__ __launch_bounds__(128) void k_prep0(
    const void* __restrict__ Wq, const void* __restrict__ bq,
    const void* __restrict__ Wk, const void* __restrict__ bk,
    const void* __restrict__ Wv, const void* __restrict__ bv,
    const void* __restrict__ Wa, const void* __restrict__ ba,
    const void* __restrict__ rel_att, const void* __restrict__ rel_msg,
    const void* __restrict__ rel_pri,
    unsigned* __restrict__ CNTP,
    int* __restrict__ FLAG, unsigned short* __restrict__ WTb,
    float* __restrict__ BC)
{
    int b = blockIdx.x;
    int j = threadIdx.x;
    if (b >= 512) {                       // zeroing part: CNTP(800000)+DONE(16)
        unsigned idx = (unsigned)(b - 512) * 128u + (unsigned)j;
        uint4 z = make_uint4(0, 0, 0, 0);
        #pragma unroll
        for (int t = 0; t < 25; ++t) {
            unsigned o = idx + (unsigned)t * 8192u;
            if (o < 200004u) ((uint4*)CNTP)[o] = z;
        }
        return;
    }
    const unsigned rp0 = ((const unsigned*)rel_pri)[0];
    const int isb = ((rp0 & 0xFFFFu) != 0u) ? 1 : 0;
    int m = b >> 7;
    int i = b & 127;          // k index
    if (b == 0 && j == 0) FLAG[0] = isb;
    if (m == 0) {
        WTb[((size_t)(0 * 128 + j)) * 128 + i] = f2bf(ldf(Wq, i * 128 + j, isb));
        if (i == 0) BC[j] = ldf(bq, j, isb);
    } else if (m == 3) {
        WTb[((size_t)(3 * 128 + j)) * 128 + i] = f2bf(ldf(Wa, i * 128 + j, isb));
        if (i == 0) BC[3 * 128 + j] = ldf(ba, j, isb);
    } else {
        const void* W    = (m == 1) ? Wk : Wv;
        const void* bias = (m == 1) ? bk : bv;
        const void* R    = (m == 1) ? rel_att : rel_msg;
        int hh = j >> 4, jj = j & 15;
        float scale = (m == 1) ? ldf(rel_pri, hh, isb) * 0.25f : 1.0f;
        float acc = 0.f, bacc = 0.f;
        #pragma unroll
        for (int l = 0; l < 16; ++l) {
            float r = ldf(R, hh * 256 + l * 16 + jj, isb);
            acc  += ldf(W, i * 128 + hh * 16 + l, isb) * r;
            bacc += ldf(bias, hh * 16 + l, isb) * r;
        }
        WTb[((size_t)(m * 128 + j)) * 128 + i] = f2bf(acc * scale);
        if (i == 0) BC[m * 128 + j] = bacc * scale;
    }
}

// ---------------------------------------------------------------------------
// Fused MFMA QKV GEMM + dst HISTOGRAM (independent work co-scheduled in one
// dispatch so they overlap on the single stream). R4-proven best: GEMM
// blocks FIRST (long blocks resident, hist backfills); R9's hist-first
// ordering regressed (62 vs 53-57us) and R10's persistent-wave version
// collapsed gather MLP (0.8 TB/s vs 3.5).
// Blocks 0..390: 128x128 GEMM tile, loop m=0..2 (A staged once); K
//   accumulators held through the V pass, KV stored interleaved ushort2.
// Blocks 391..3515: histogram into line-padded CNTP[d*16]; atomic return
//   value IS the edge's rank within its dst bucket -> RANKS (ushort).
// ---------------------------------------------------------------------------
#define NBG 391   // ceil(NN/128)
#define NHB 3125  // 3125*256 == NE exactly
#define NSB 98    // ceil(NN/512)
#define NFB 782   // ceil(NN/64) final tiles
__global__ __launch_bounds__(256, 2) void k_qkvh(
    const void* __restrict__ h, const unsigned short* __restrict__ WTb,
    const float* __restrict__ BC, const int* __restrict__ FLAG,
    unsigned short* __restrict__ Qb, unsigned short* __restrict__ KVb,
    const int* __restrict__ dst,
    unsigned* __restrict__ CNTP, unsigned short* __restrict__ RANKS)
{
    __shared__ __align__(16) unsigned short Ah[128][136];   // +8 pad
    __shared__ __align__(16) unsigned short Bh[128][136];
    const int tid = threadIdx.x;

    if (blockIdx.x >= NBG) {
        // ---------------- histogram part ----------------
        int e = (blockIdx.x - NBG) * 256 + tid;
        unsigned r = atomicAdd(&CNTP[(unsigned)dst[e] << 4], 1u);
        RANKS[e] = (unsigned short)r;
        return;
    }

    // ---------------- QKV GEMM part ----------------
    const int isb = FLAG[0];
    const int rowBase = blockIdx.x * 128;

    if (isb) {
        #pragma unroll
        for (int i = 0; i < 8; ++i) {
            int lin = tid + i * 256;
            int row = lin >> 4, kc = (lin & 15) * 8;
            int gr = rowBase + row;
            uint4 u = make_uint4(0, 0, 0, 0);
            if (gr < NN) u = *(const uint4*)((const unsigned short*)h + (size_t)gr * 128 + kc);
            *(uint4*)&Ah[row][kc] = u;
        }
    } else {
        #pragma unroll
        for (int i = 0; i < 16; ++i) {
            int lin = tid + i * 256;
            int row = lin >> 5, c4 = (lin & 31) * 4;
            int gr = rowBase + row;
            ushort4 o = make_ushort4(0, 0, 0, 0);
            if (gr < NN) {
                float4 f = *(const float4*)((const float*)h + (size_t)gr * 128 + c4);
                o.x = f2bf(f.x); o.y = f2bf(f.y); o.z = f2bf(f.z); o.w = f2bf(f.w);
            }
            *(ushort4*)&Ah[row][c4] = o;
        }
    }

    const int w = tid >> 6, l = tid & 63;
    const int lr = l & 15, q = l >> 4;
    v4f accK[2][8];

    for (int m = 0; m < 3; ++m) {
        if (m) __syncthreads();
        #pragma unroll
        for (int i = 0; i < 8; ++i) {
            int lin = tid + i * 256;
            int col = lin >> 4, kc = (lin & 15) * 8;
            uint4 u = *(const uint4*)(WTb + ((size_t)(m * 128 + col)) * 128 + kc);
            *(uint4*)&Bh[col][kc] = u;
        }
        __syncthreads();

        v4f acc[2][8];
        #pragma unroll
        for (int rt = 0; rt < 2; ++rt)
            #pragma unroll
            for (int nt = 0; nt < 8; ++nt) {
                float bj = BC[m * 128 + nt * 16 + lr];
                acc[rt][nt] = (v4f){bj, bj, bj, bj};
            }
        #pragma unroll
        for (int kk = 0; kk < 4; ++kk) {
            v8bf a0 = *(const v8bf*)&Ah[w * 32 +  0 + lr][kk * 32 + q * 8];
            v8bf a1 = *(const v8bf*)&Ah[w * 32 + 16 + lr][kk * 32 + q * 8];
            #pragma unroll
            for (int nt = 0; nt < 8; ++nt) {
                v8bf b = *(const v8bf*)&Bh[nt * 16 + lr][kk * 32 + q * 8];
                acc[0][nt] = __builtin_amdgcn_mfma_f32_16x16x32_bf16(a0, b, acc[0][nt], 0, 0, 0);
                acc[1][nt] = __builtin_amdgcn_mfma_f32_16x16x32_bf16(a1, b, acc[1][nt], 0, 0, 0);
            }
        }
        if (m == 0) {
            #pragma unroll
            for (int rt = 0; rt < 2; ++rt)
                #pragma unroll
                for (int nt = 0; nt < 8; ++nt)
                    #pragma unroll
                    for (int r = 0; r < 4; ++r) {
                        int row = rowBase + w * 32 + rt * 16 + q * 4 + r;
                        if (row < NN)
                            Qb[(size_t)row * 128 + nt * 16 + lr] = f2bf(acc[rt][nt][r]);
                    }
        } else if (m == 1) {
            #pragma unroll
            for (int rt = 0; rt < 2; ++rt)
                #pragma unroll
                for (int nt = 0; nt < 8; ++nt) accK[rt][nt] = acc[rt][nt];
        } else {
            #pragma unroll
            for (int rt = 0; rt < 2; ++rt)
                #pragma unroll
                for (int nt = 0; nt < 8; ++nt)
                    #pragma unroll
                    for (int r = 0; r < 4; ++r) {
                        int row = rowBase + w * 32 + rt * 16 + q * 4 + r;
                        if (row < NN) {
                            ushort2 kv;
                            kv.x = f2bf(accK[rt][nt][r]);   // K channel
                            kv.y = f2bf(acc[rt][nt][r]);    // V channel
                            *(ushort2*)&KVb[(size_t)row * 256 + (nt * 16 + lr) * 2] = kv;
                        }
                    }
        }
    }
}

// ---------------------------------------------------------------------------
// CSR scan (512 nodes/block), last-block pattern -> BOFF.
// ---------------------------------------------------------------------------
__global__ __launch_bounds__(256) void k_scan(
    const unsigned* __restrict__ CNTP,
    unsigned* __restrict__ RPS, unsigned* __restrict__ BSUM,
    unsigned* __restrict__ BOFF, unsigned* __restrict__ DONE)
{
    __shared__ unsigned shs[256];
    __shared__ int lastFlag;
    const int tid = threadIdx.x;
    int sb = blockIdx.x;
    int g0 = sb * 512 + tid * 2, g1 = g0 + 1;
    unsigned v0 = (g0 < NN) ? CNTP[(size_t)g0 << 4] : 0u;
    unsigned v1 = (g1 < NN) ? CNTP[(size_t)g1 << 4] : 0u;
    unsigned pv = v0 + v1;
    shs[tid] = pv;
    __syncthreads();
    #pragma unroll
    for (int off = 1; off < 256; off <<= 1) {
        unsigned t = 0;
        if (tid >= off) t = shs[tid - off];
        __syncthreads();
        if (tid >= off) shs[tid] += t;
        __syncthreads();
    }
    unsigned excl = shs[tid] - pv;
    if (g0 < NN) RPS[g0] = excl;
    if (g1 < NN) RPS[g1] = excl + v0;
    if (tid == 255) atomicExch(&BSUM[sb], shs[255]);
    __syncthreads();
    if (tid == 0) {
        __threadfence();
        lastFlag = (atomicAdd(DONE, 1u) == NSB - 1);
    }
    __syncthreads();
    if (!lastFlag) return;
    unsigned bv = (tid < NSB) ? atomicAdd(&BSUM[tid], 0u) : 0u;
    __syncthreads();
    shs[tid] = bv;
    __syncthreads();
    #pragma unroll
    for (int off = 1; off < 256; off <<= 1) {
        unsigned t = 0;
        if (tid >= off) t = shs[tid - off];
        __syncthreads();
        if (tid >= off) shs[tid] += t;
        __syncthreads();
    }
    if (tid < NSB) BOFF[tid] = shs[tid] - bv;
}

// ---------------------------------------------------------------------------
// CSR fill, ATOMIC-FREE: pos = RPS[d] + BOFF + RANKS[e]. ESRC is ushort.
// Also materializes ROW[d] = RPS[d] + BOFF[d>>9] for k_attn's startup.
// ---------------------------------------------------------------------------
__global__ __launch_bounds__(256) void k_fill(
    const int* __restrict__ src, const int* __restrict__ dst,
    const unsigned short* __restrict__ RANKS,
    const unsigned* __restrict__ RPS, const unsigned* __restrict__ BOFF,
    unsigned short* __restrict__ ESRC, unsigned* __restrict__ ROW)
{
    int t = blockIdx.x * 256 + threadIdx.x;
    if (t < NN) ROW[t] = RPS[t] + BOFF[t >> 9];
    if (t >= NE / 2) return;
    int e = t * 2;
    const int2 d2 = *(const int2*)(dst + e);
    const int2 s2 = *(const int2*)(src + e);
    const ushort2 r2 = *(const ushort2*)(RANKS + e);
    unsigned p0 = RPS[d2.x] + BOFF[d2.x >> 9] + r2.x;
    unsigned p1 = RPS[d2.y] + BOFF[d2.y >> 9] + r2.y;
    ESRC[p0] = (unsigned short)s2.x;
    ESRC[p1] = (unsigned short)s2.y;
}

// ---------------------------------------------------------------------------
// Fused attention: one wave per dst node, 32 lanes per edge (2 edges/round),
// 8-edge rounds. Depth-2 software pipeline. Full rounds unmasked; only the
// tail round predicates. 32-bit gather offsets. No-max softmax.
// At a pattern-specific memory-system ceiling: L2-miss traffic 179.6 MB
// equals the structural minimum (8 XCDs x 50K*(1-e^-2) rows x 512B) and
// delivery saturates ~3.5 TB/s. Short-lived waves (one node each) are
// ESSENTIAL: R10's persistent-wave version collapsed to 0.8 TB/s.
// ---------------------------------------------------------------------------
__global__ __launch_bounds__(256) void k_attn(
    const unsigned* __restrict__ ROW,
    const unsigned short* __restrict__ ESRC,
    const unsigned short* __restrict__ Qb, const unsigned short* __restrict__ KVb,
    unsigned short* __restrict__ Tb)
{
    int d = (blockIdx.x * 256 + threadIdx.x) >> 6;
    int lane = threadIdx.x & 63;
    int hl = lane >> 5;        // which edge of the pair
    int sub = lane & 31;       // channel group: channels sub*4 .. sub*4+3
    const float LOG2E = 1.4426950408889634f;

    unsigned beg = ROW[d];
    unsigned end = (d == NN - 1) ? (unsigned)NE : ROW[d + 1];

    const ushort4 qu = *(const ushort4*)(Qb + (size_t)d * 128 + sub * 4);
    float q0 = bf2f(qu.x) * LOG2E, q1 = bf2f(qu.y) * LOG2E;
    float q2 = bf2f(qu.z) * LOG2E, q3 = bf2f(qu.w) * LOG2E;

    float s = 0.f, o0 = 0.f, o1 = 0.f, o2 = 0.f, o3 = 0.f;
    int n = (int)(end - beg);

    // kv layout per lane: [K0,V0,K1,V1,K2,V2,K3,V3] for channels sub*4..+3
#define ATT_F(kv) {                                                         \
        float p = q0 * bf2f(kv[0]) + q1 * bf2f(kv[2])                       \
                + q2 * bf2f(kv[4]) + q3 * bf2f(kv[6]);                      \
        p += __shfl_xor(p, 1);                                              \
        p += __shfl_xor(p, 2);                                              \
        float wgt = EXP2F(p);                                               \
        s  += wgt;                                                          \
        o0 += wgt * bf2f(kv[1]); o1 += wgt * bf2f(kv[3]);                   \
        o2 += wgt * bf2f(kv[5]); o3 += wgt * bf2f(kv[7]); }
#define ATT_T(kv, idx) {                                                    \
        float p = q0 * bf2f(kv[0]) + q1 * bf2f(kv[2])                       \
                + q2 * bf2f(kv[4]) + q3 * bf2f(kv[6]);                      \
        p += __shfl_xor(p, 1);                                              \
        p += __shfl_xor(p, 2);                                              \
        float wgt = ((idx) < end) ? EXP2F(p) : 0.f;                         \
        s  += wgt;                                                          \
        o0 += wgt * bf2f(kv[1]); o1 += wgt * bf2f(kv[3]);                   \
        o2 += wgt * bf2f(kv[5]); o3 += wgt * bf2f(kv[7]); }
#define GATH(sid) (*(const v8us*)(KVB + (((unsigned)(sid) << 9) + voff)))

    if (n > 0) {
        const unsigned char* KVB = (const unsigned char*)KVb;
        const unsigned voff = (unsigned)(sub * 16);   // byte offset in KV row
        const unsigned last = end - 1;
        const int RT = (n + 7) >> 3;                  // 8-edge rounds
        const int tail = n & 7;                       // 0 => last round full
        const unsigned b0 = beg + (unsigned)hl;

        // round 0 sids + gathers
        unsigned sA0 = ESRC[uminu(b0 + 0u, last)];
        unsigned sA1 = ESRC[uminu(b0 + 2u, last)];
        unsigned sA2 = ESRC[uminu(b0 + 4u, last)];
        unsigned sA3 = ESRC[uminu(b0 + 6u, last)];
        v8us kA0 = GATH(sA0), kA1 = GATH(sA1), kA2 = GATH(sA2), kA3 = GATH(sA3);
        // round 1 sids
        unsigned sB0 = 0, sB1 = 0, sB2 = 0, sB3 = 0;
        if (RT > 1) {
            unsigned b1 = b0 + 8u;
            sB0 = ESRC[uminu(b1 + 0u, last)];
            sB1 = ESRC[uminu(b1 + 2u, last)];
            sB2 = ESRC[uminu(b1 + 4u, last)];
            sB3 = ESRC[uminu(b1 + 6u, last)];
        }

        for (int r = 0; r < RT; ++r) {
            v8us kB0 = kA0, kB1 = kA1, kB2 = kA2, kB3 = kA3;
            if (r + 1 < RT) {            // KV gathers for round r+1
                kB0 = GATH(sB0); kB1 = GATH(sB1);
                kB2 = GATH(sB2); kB3 = GATH(sB3);
            }
            unsigned sC0 = sB0, sC1 = sB1, sC2 = sB2, sC3 = sB3;
            if (r + 2 < RT) {            // sids for round r+2
                unsigned b2 = b0 + (unsigned)(8 * (r + 2));
                sC0 = ESRC[uminu(b2 + 0u, last)];
                sC1 = ESRC[uminu(b2 + 2u, last)];
                sC2 = ESRC[uminu(b2 + 4u, last)];
                sC3 = ESRC[uminu(b2 + 6u, last)];
            }
            if (r == RT - 1 && tail) {   // masked tail round
                unsigned base = beg + (unsigned)(8 * r) + (unsigned)hl;
                ATT_T(kA0, base + 0u);
                ATT_T(kA1, base + 2u);
                ATT_T(kA2, base + 4u);
                ATT_T(kA3, base + 6u);
            } else {                     // full round: no predication
                ATT_F(kA0); ATT_F(kA1); ATT_F(kA2); ATT_F(kA3);
            }
            kA0 = kB0; kA1 = kB1; kA2 = kB2; kA3 = kB3;
            sB0 = sC0; sB1 = sC1; sB2 = sC2; sB3 = sC3;
        }
    }
#undef ATT_F
#undef ATT_T
#undef GATH

    // combine the two 32-lane halves
    s  += __shfl_xor(s, 32);
    o0 += __shfl_xor(o0, 32);
    o1 += __shfl_xor(o1, 32);
    o2 += __shfl_xor(o2, 32);
    o3 += __shfl_xor(o3, 32);
    float r = (s > 0.f) ? (1.0f / s) : 0.f;
    if (hl == 0) {
        ushort4 o;
        o.x = f2bf(o0 * r); o.y = f2bf(o1 * r);
        o.z = f2bf(o2 * r); o.w = f2bf(o3 * r);
        *(ushort4*)(Tb + (size_t)d * 128 + sub * 4) = o;
    }
}

// ---------------------------------------------------------------------------
// MFMA final GEMM + sigmoid-skip blend. R12: 64-row A-tile (17.4 KB) +
// B-panel in LDS (34.8 KB) = 52.2 KB -> 3 blocks/CU (12 waves/CU, +50% vs
// the 69.6 KB 128-row version's 2 blocks/CU), 782 blocks (2x wave churn).
// B stays in LDS (B-direct-from-L2 proven latency trap in R6/R8); A path
// identical to the refcheck-passed R7/R8 final.
// ---------------------------------------------------------------------------
__global__ __launch_bounds__(256) void k_final_m(
    const unsigned short* __restrict__ Tb, const unsigned short* __restrict__ WTb,
    const float* __restrict__ BC, const void* __restrict__ h,
    const void* __restrict__ skip, const int* __restrict__ FLAG,
    void* __restrict__ out)
{
    __shared__ __align__(16) unsigned short Ah[64][136];    // 17.4 KB
    __shared__ __align__(16) unsigned short Bh[128][136];   // 34.8 KB
    const int isb = FLAG[0];
    const int tid = threadIdx.x;
    const int rowBase = blockIdx.x * 64;

    #pragma unroll
    for (int i = 0; i < 4; ++i) {
        int lin = tid + i * 256;
        int row = lin >> 4, kc = (lin & 15) * 8;
        int gr = rowBase + row;
        uint4 u = make_uint4(0, 0, 0, 0);
        if (gr < NN) u = *(const uint4*)(Tb + (size_t)gr * 128 + kc);
        *(uint4*)&Ah[row][kc] = u;
    }
    #pragma unroll
    for (int i = 0; i < 8; ++i) {
        int lin = tid + i * 256;
        int col = lin >> 4, kc = (lin & 15) * 8;
        uint4 u = *(const uint4*)(WTb + ((size_t)(3 * 128 + col)) * 128 + kc);
        *(uint4*)&Bh[col][kc] = u;
    }
    __syncthreads();

    const int w = tid >> 6, l = tid & 63;
    const int lr = l & 15, q = l >> 4;

    v4f acc[8];
    #pragma unroll
    for (int nt = 0; nt < 8; ++nt) {
        float bj = BC[3 * 128 + nt * 16 + lr];
        acc[nt] = (v4f){bj, bj, bj, bj};
    }
    #pragma unroll
    for (int kk = 0; kk < 4; ++kk) {
        v8bf a = *(const v8bf*)&Ah[w * 16 + lr][kk * 32 + q * 8];
        #pragma unroll
        for (int nt = 0; nt < 8; ++nt) {
            v8bf b = *(const v8bf*)&Bh[nt * 16 + lr][kk * 32 + q * 8];
            acc[nt] = __builtin_amdgcn_mfma_f32_16x16x32_bf16(a, b, acc[nt], 0, 0, 0);
        }
    }
    float skipv = ldf(skip, 0, isb);
    float alpha = 1.0f / (1.0f + __expf(-skipv));
    float beta = 1.0f - alpha;
    #pragma unroll
    for (int nt = 0; nt < 8; ++nt) {
        #pragma unroll
        for (int r = 0; r < 4; ++r) {
            int row = rowBase + w * 16 + q * 4 + r;
            if (row < NN) {
                size_t off = (size_t)row * 128 + nt * 16 + lr;
                float hv = ldf(h, off, isb);
                float o = alpha * acc[nt][r] + beta * hv;
                if (isb) ((unsigned short*)out)[off] = f2bf(o);
                else     ((float*)out)[off] = o;
            }
        }
    }
}

// ---------------------------------------------------------------------------
// ws layout (u32 offsets): FLAG 16 | BC 512 | WTb 32768 | CNTP 800000 |
// DONE 16 | RANKS 400000 (800000 ushort) | RPS 50048 | BSUM 128 | BOFF 128 |
// ROW 50048 | Tb NN*128us | ESRC NE ushort | Qb NN*128us | KVb NN*256us
// total ~58 MB
// ---------------------------------------------------------------------------
extern "C" void kernel_launch(void* const* d_in, const int* in_sizes, int n_in,
                              void* d_out, int out_size, void* d_ws, size_t ws_size,
                              hipStream_t stream)
{
    const void* h  = d_in[0];
    const int* src = (const int*)d_in[1];
    const int* dst = (const int*)d_in[2];
    const void* Wk = d_in[3];
    const void* bk = d_in[4];
    const void* Wq = d_in[5];
    const void* bq = d_in[6];
    const void* Wv = d_in[7];
    const void* bv = d_in[8];
    const void* Wa = d_in[9];
    const void* ba = d_in[10];
    const void* rel_att = d_in[11];
    const void* rel_msg = d_in[12];
    const void* rel_pri = d_in[13];
    const void* skip    = d_in[14];

    float* F = (float*)d_ws;
    int* FLAG      = (int*)F;
    float* BC      = F + 16;
    unsigned short* WTb = (unsigned short*)(BC + 512);
    unsigned* CNTP = (unsigned*)((float*)(BC + 512) + 32768);
    unsigned* DONE = CNTP + 800000;
    unsigned short* RANKS = (unsigned short*)(DONE + 16);
    unsigned* RPS  = (unsigned*)(RANKS + 800000);
    unsigned* BSUM = RPS + 50048;
    unsigned* BOFF = BSUM + 128;
    unsigned* ROW  = BOFF + 128;
    unsigned short* Tb = (unsigned short*)(ROW + 50048);
    unsigned short* ESRC = Tb + (size_t)NN * 128;
    unsigned short* Qb  = ESRC + NE;
    unsigned short* KVb = Qb + (size_t)NN * 128;

    // 1. weights/BC/FLAG + zero CNTP|DONE (memset folded in)
    k_prep0<<<512 + 64, 128, 0, stream>>>(Wq, bq, Wk, bk, Wv, bv, Wa, ba,
                                          rel_att, rel_msg, rel_pri,
                                          CNTP, FLAG, WTb, BC);
    // 2. QKV GEMM (first in grid) overlapped with dst histogram
    k_qkvh<<<NBG + NHB, 256, 0, stream>>>(h, WTb, BC, FLAG, Qb, KVb,
                                          dst, CNTP, RANKS);
    // 3. CSR scan
    k_scan<<<NSB, 256, 0, stream>>>(CNTP, RPS, BSUM, BOFF, DONE);
    // 4. CSR fill + ROW
    k_fill<<<(NE / 2 + 255) / 256, 256, 0, stream>>>(src, dst, RANKS, RPS, BOFF, ESRC, ROW);
    // 5. fused attention
    k_attn<<<(NN * 64) / 256, 256, 0, stream>>>(ROW, ESRC, Qb, KVb, Tb);
    // 6. final GEMM + skip blend (64-row tiles, 3 blocks/CU)
    k_final_m<<<NFB, 256, 0, stream>>>(Tb, WTb, BC, h, skip, FLAG, d_out);
}